// Round 1
// baseline (240.490 us; speedup 1.0000x reference)
//
#include <hip/hip_runtime.h>
#include <hip/hip_bf16.h>

typedef __attribute__((ext_vector_type(4))) float          f32x4;
typedef __attribute__((ext_vector_type(8))) short          bf16x8;
typedef __attribute__((ext_vector_type(8))) unsigned short u16x8;

#define BDIM 256
#define BM 128
#define BN 128
#define BK 64
#define KTOT 512
#define NK (KTOT / BK)

__device__ __forceinline__ float fast_tanh(float x) {
    float ax = __builtin_fabsf(x);
    float e  = __expf(-2.0f * ax);             // in (0,1]
    float t  = (1.0f - e) * __builtin_amdgcn_rcpf(1.0f + e);
    return __builtin_copysignf(t, x);
}

__device__ __forceinline__ unsigned short f2bf(float f) {
    // round-to-nearest-even f32 -> bf16 (values are finite, no NaN handling)
    unsigned u = __float_as_uint(f);
    unsigned r = 0x7FFFu + ((u >> 16) & 1u);
    return (unsigned short)((u + r) >> 16);
}

__global__ __launch_bounds__(BDIM, 2) void joiner_kernel(
    const float* __restrict__ enc,   // (B*T, C) = (1600, 512)
    const float* __restrict__ pred,  // (B*U, C) = (400, 512)
    const float* __restrict__ W,     // (V, C)   = (512, 512)
    const float* __restrict__ bias,  // (V,)
    float* __restrict__ out)         // (B*T*U, V) = (160000, 512)
{
    constexpr int Uu = 100, TU = 40000, Cc = 512, Vv = 512;

    __shared__ unsigned short As[2][BM * BK];
    __shared__ unsigned short Ws[2][BN * BK];

    const int tid  = threadIdx.x;
    const int lane = tid & 63;
    const int w    = tid >> 6;
    const int wm   = w >> 1, wn = w & 1;

    const int bidM = blockIdx.x >> 2;   // 0..1249
    const int bidN = blockIdx.x & 3;    // 0..3

    // ---- per-slot source pointers (4 row-slots each; g = k-subgroup of 8) ----
    const int r0 = tid >> 3;            // 0..31
    const int g  = tid & 7;             // 0..7
    const float* encP[4];
    const float* predP[4];
    const float* wP[4];
#pragma unroll
    for (int s = 0; s < 4; ++s) {
        int r  = r0 + s * 32;           // tile row 0..127
        int m  = bidM * BM + r;         // global (b,t,u) row
        int et = m / Uu;                // b*T + t   (enc row)
        int u  = m - et * Uu;
        int bb = m / TU;                // batch
        int pr = bb * Uu + u;           // pred row
        encP[s]  = enc  + et * Cc + g * 8;
        predP[s] = pred + pr * Cc + g * 8;
        wP[s]    = W + (bidN * BN + r) * Cc + g * 8;
    }

    // staged registers (issue-early / write-late)
    f32x4 eR[4][2], pR[4][2], wR[4][2];

    auto stageLoad = [&](int ks) {
        const int kb = ks * BK;
#pragma unroll
        for (int s = 0; s < 4; ++s) {
            eR[s][0] = *(const f32x4*)(encP[s] + kb);
            eR[s][1] = *(const f32x4*)(encP[s] + kb + 4);
            pR[s][0] = *(const f32x4*)(predP[s] + kb);
            pR[s][1] = *(const f32x4*)(predP[s] + kb + 4);
            wR[s][0] = *(const f32x4*)(wP[s] + kb);
            wR[s][1] = *(const f32x4*)(wP[s] + kb + 4);
        }
    };

    auto stageWrite = [&](int buf) {
#pragma unroll
        for (int s = 0; s < 4; ++s) {
            int r    = r0 + s * 32;
            int byte = r * (BK * 2) + g * 16;
            byte ^= ((r & 7) << 4);                 // T2 XOR swizzle
            u16x8 av, wv;
#pragma unroll
            for (int h = 0; h < 2; ++h) {
#pragma unroll
                for (int j = 0; j < 4; ++j) {
                    float x = eR[s][h][j] + pR[s][h][j];
                    av[h * 4 + j] = f2bf(fast_tanh(x));
                    wv[h * 4 + j] = f2bf(wR[s][h][j]);
                }
            }
            *(u16x8*)((char*)(&As[buf][0]) + byte) = av;
            *(u16x8*)((char*)(&Ws[buf][0]) + byte) = wv;
        }
    };

    f32x4 acc[4][4];
#pragma unroll
    for (int i = 0; i < 4; ++i)
#pragma unroll
        for (int j = 0; j < 4; ++j)
            acc[i][j] = (f32x4){0.f, 0.f, 0.f, 0.f};

    const int lc = lane & 15;
    const int lk = (lane >> 4) * 8;     // k-offset within 32 (elements)

    auto compute = [&](int buf) {
#pragma unroll
        for (int kk = 0; kk < 2; ++kk) {
            bf16x8 af[4], bfr[4];
#pragma unroll
            for (int f = 0; f < 4; ++f) {
                int rowA  = wm * 64 + f * 16 + lc;
                int byteA = rowA * (BK * 2) + (kk * 32 + lk) * 2;
                byteA ^= ((rowA & 7) << 4);
                af[f] = *(const bf16x8*)((const char*)(&As[buf][0]) + byteA);
                int rowB  = wn * 64 + f * 16 + lc;
                int byteB = rowB * (BK * 2) + (kk * 32 + lk) * 2;
                byteB ^= ((rowB & 7) << 4);
                bfr[f] = *(const bf16x8*)((const char*)(&Ws[buf][0]) + byteB);
            }
#pragma unroll
            for (int i = 0; i < 4; ++i)
#pragma unroll
                for (int j = 0; j < 4; ++j)
                    acc[i][j] = __builtin_amdgcn_mfma_f32_16x16x32_bf16(
                        af[i], bfr[j], acc[i][j], 0, 0, 0);
        }
    };

    // ---- main loop: double-buffered, T14 issue-early/write-late ----
    stageLoad(0);
    stageWrite(0);
    __syncthreads();
    int buf = 0;
    for (int ks = 0; ks < NK; ++ks) {
        if (ks + 1 < NK) stageLoad(ks + 1);   // global loads in flight
        compute(buf);                          // MFMA on current tiles
        if (ks + 1 < NK) stageWrite(buf ^ 1); // tanh/cvt/ds_write after compute
        __syncthreads();
        buf ^= 1;
    }

    // ---- epilogue: C/D layout col=lane&15, row=(lane>>4)*4+reg ----
    const int lr      = (lane >> 4) * 4;
    const int rowBase = bidM * BM + wm * 64 + lr;
    const int colBase = bidN * BN + wn * 64 + lc;
    float bia[4];
#pragma unroll
    for (int j = 0; j < 4; ++j) bia[j] = bias[colBase + j * 16];
#pragma unroll
    for (int i = 0; i < 4; ++i) {
#pragma unroll
        for (int j = 0; j < 4; ++j) {
#pragma unroll
            for (int q = 0; q < 4; ++q) {
                out[(rowBase + i * 16 + q) * Vv + colBase + j * 16] =
                    acc[i][j][q] + bia[j];
            }
        }
    }
}

extern "C" void kernel_launch(void* const* d_in, const int* in_sizes, int n_in,
                              void* d_out, int out_size, void* d_ws, size_t ws_size,
                              hipStream_t stream) {
    const float* enc  = (const float*)d_in[0];
    const float* pred = (const float*)d_in[1];
    const float* W    = (const float*)d_in[2];
    const float* bias = (const float*)d_in[3];
    float* out        = (float*)d_out;

    // M = 4*400*100 = 160000 -> 1250 M-blocks; N = 512 -> 4 N-blocks
    dim3 grid(1250 * 4);
    joiner_kernel<<<grid, BDIM, 0, stream>>>(enc, pred, W, bias, out);
}

// Round 2
// 168.369 us; speedup vs baseline: 1.4284x; 1.4284x over previous
//
#include <hip/hip_runtime.h>
#include <hip/hip_bf16.h>

typedef __attribute__((ext_vector_type(4))) float          f32x4;
typedef __attribute__((ext_vector_type(8))) short          bf16x8;
typedef __attribute__((ext_vector_type(8))) unsigned short u16x8;

#define Cc 512
#define Vv 512
#define BM 64

// Pre-swizzled bf16 copy of W, written by prep kernel each launch.
// Element (v,k) -> W2[((v>>4)*16 + (k>>5))*512 + ((v&15) + 16*((k>>3)&3))*8 + (k&7)]
// so a wave's 64 lanes load one MFMA B-fragment as one coalesced 1KB read.
__device__ unsigned short g_W2[Vv * Cc];

__device__ __forceinline__ unsigned short f2bf(float f) {
    unsigned u = __float_as_uint(f);
    unsigned r = 0x7FFFu + ((u >> 16) & 1u);
    return (unsigned short)((u + r) >> 16);
}

__device__ __forceinline__ float fast_tanh(float x) {
    // tanh(x) = 1 - 2/(exp(2x)+1); handles +/-inf saturation naturally
    float e = __expf(2.0f * x);
    return 1.0f - 2.0f * __builtin_amdgcn_rcpf(e + 1.0f);
}

__global__ __launch_bounds__(256) void prep_w_kernel(const float* __restrict__ W) {
    int gid = blockIdx.x * 256 + threadIdx.x;   // 0..32767, 8 elems each
    int v = gid >> 6;
    int k = (gid & 63) * 8;
    f32x4 a = *(const f32x4*)(W + v * Cc + k);
    f32x4 b = *(const f32x4*)(W + v * Cc + k + 4);
    u16x8 o;
#pragma unroll
    for (int j = 0; j < 4; ++j) {
        o[j]     = f2bf(a[j]);
        o[4 + j] = f2bf(b[j]);
    }
    int frag = (v >> 4) * 16 + (k >> 5);
    int lane = (v & 15) + 16 * ((k >> 3) & 3);
    *(u16x8*)(&g_W2[frag * 512 + lane * 8]) = o;
}

__global__ __launch_bounds__(256, 2) void joiner_main(
    const float* __restrict__ enc,   // (1600, 512)
    const float* __restrict__ pred,  // (400, 512)
    const float* __restrict__ bias,  // (512,)
    float* __restrict__ out)         // (160000, 512)
{
    __shared__ unsigned short As[BM * Cc];   // 64 KB, XOR-swizzled rows

    const int tid = threadIdx.x;
    const int bid = blockIdx.x;

    // ---- stage: A = tanh(enc+pred) -> bf16 LDS, full K=512, ONCE ----
    {
        const int r = tid >> 2;          // 0..63 (tile row)
        const int q = tid & 3;           // k-quarter (128 elems)
        const int m  = bid * BM + r;
        const int et = m / 100;          // enc row (b*T + t)
        const int u  = m - et * 100;
        const int bb = m / 40000;
        const int pr = bb * 100 + u;     // pred row
        const float* eP = enc + et * Cc;
        const float* pP = pred + pr * Cc;
        char* asBase = (char*)As;
        const int swz = (r & 7) << 4;
#pragma unroll
        for (int c = 0; c < 4; ++c) {
            const int k0 = q * 128 + c * 32;
            f32x4 ev[8], pv[8];
#pragma unroll
            for (int j = 0; j < 8; ++j) {
                ev[j] = *(const f32x4*)(eP + k0 + j * 4);
                pv[j] = *(const f32x4*)(pP + k0 + j * 4);
            }
#pragma unroll
            for (int s = 0; s < 4; ++s) {
                u16x8 o;
#pragma unroll
                for (int e2 = 0; e2 < 8; ++e2) {
                    int idx = s * 8 + e2;
                    float x = ev[idx >> 2][idx & 3] + pv[idx >> 2][idx & 3];
                    o[e2] = f2bf(fast_tanh(x));
                }
                int byte = r * 1024 + (k0 + s * 8) * 2;
                *(u16x8*)(asBase + (byte ^ swz)) = o;
            }
        }
    }
    __syncthreads();   // the only barrier in the kernel

    // ---- compute: 64 rows x full V=512 per block ----
    const int lane = tid & 63;
    const int w    = tid >> 6;          // wave 0..3 -> V columns w*64
    const int lc   = lane & 15;
    const int lkB  = (lane >> 4) << 4;  // k byte-offset within 32-elem step

    f32x4 acc[2][4][4];
#pragma unroll
    for (int h = 0; h < 2; ++h)
#pragma unroll
        for (int i = 0; i < 4; ++i)
#pragma unroll
            for (int j = 0; j < 4; ++j)
                acc[h][i][j] = (f32x4){0.f, 0.f, 0.f, 0.f};

    const char* asB = (const char*)As;
    const unsigned short* wb = &g_W2[0];

#pragma unroll 2
    for (int ks = 0; ks < 16; ++ks) {
        bf16x8 af[4];
#pragma unroll
        for (int i = 0; i < 4; ++i) {
            int row  = i * 16 + lc;
            int byte = row * 1024 + ks * 64 + lkB;
            byte ^= (row & 7) << 4;
            af[i] = *(const bf16x8*)(asB + byte);
        }
#pragma unroll
        for (int h = 0; h < 2; ++h) {
            bf16x8 bf[4];
#pragma unroll
            for (int j = 0; j < 4; ++j) {
                int vg = h * 16 + w * 4 + j;   // v-group (16 rows of W)
                bf[j] = *(const bf16x8*)(wb + ((vg * 16 + ks) << 9) + lane * 8);
            }
            __builtin_amdgcn_s_setprio(1);
#pragma unroll
            for (int i = 0; i < 4; ++i)
#pragma unroll
                for (int j = 0; j < 4; ++j)
                    acc[h][i][j] = __builtin_amdgcn_mfma_f32_16x16x32_bf16(
                        af[i], bf[j], acc[h][i][j], 0, 0, 0);
            __builtin_amdgcn_s_setprio(0);
        }
    }

    // ---- epilogue: C/D layout col=lane&15, row=(lane>>4)*4+q ----
    const int lr = (lane >> 4) << 2;
    const int rowBase = bid * BM;
    float bia[2][4];
#pragma unroll
    for (int h = 0; h < 2; ++h)
#pragma unroll
        for (int j = 0; j < 4; ++j)
            bia[h][j] = bias[h * 256 + w * 64 + j * 16 + lc];
#pragma unroll
    for (int i = 0; i < 4; ++i) {
#pragma unroll
        for (int q = 0; q < 4; ++q) {
            int row = rowBase + i * 16 + lr + q;
            float* op = out + row * Vv;
#pragma unroll
            for (int h = 0; h < 2; ++h)
#pragma unroll
                for (int j = 0; j < 4; ++j)
                    op[h * 256 + w * 64 + j * 16 + lc] = acc[h][i][j][q] + bia[h][j];
        }
    }
}

extern "C" void kernel_launch(void* const* d_in, const int* in_sizes, int n_in,
                              void* d_out, int out_size, void* d_ws, size_t ws_size,
                              hipStream_t stream) {
    const float* enc  = (const float*)d_in[0];
    const float* pred = (const float*)d_in[1];
    const float* W    = (const float*)d_in[2];
    const float* bias = (const float*)d_in[3];
    float* out        = (float*)d_out;

    prep_w_kernel<<<128, 256, 0, stream>>>(W);
    // M = 160000 rows / BM=64 -> 2500 blocks, each does full V=512
    joiner_main<<<2500, 256, 0, stream>>>(enc, pred, bias, out);
}

// Round 3
// 123.796 us; speedup vs baseline: 1.9426x; 1.3601x over previous
//
#include <hip/hip_runtime.h>
#include <hip/hip_bf16.h>

typedef __attribute__((ext_vector_type(4))) float          f32x4;
typedef __attribute__((ext_vector_type(8))) short          bf16x8;
typedef __attribute__((ext_vector_type(8))) unsigned short u16x8;

#define Cc 512
#define Vv 512
#define BM 64

// Pre-swizzled bf16 W (MFMA B-fragment order) + f32 tanh of enc/pred rows.
__device__ unsigned short g_W2[Vv * Cc];
__device__ float g_ta[1600 * Cc];
__device__ float g_tp[400 * Cc];

__device__ __forceinline__ unsigned short f2bf(float f) {
    unsigned u = __float_as_uint(f);
    unsigned r = 0x7FFFu + ((u >> 16) & 1u);
    return (unsigned short)((u + r) >> 16);
}

__device__ __forceinline__ float fast_tanh(float x) {
    float e = __expf(2.0f * x);
    return 1.0f - 2.0f * __builtin_amdgcn_rcpf(e + 1.0f);
}

// One prep kernel: blocks [0,128) -> W2 swizzle; [128,528) -> tanh(enc); [528,628) -> tanh(pred)
__global__ __launch_bounds__(256) void prep_kernel(
    const float* __restrict__ W, const float* __restrict__ enc,
    const float* __restrict__ pred)
{
    const int b = blockIdx.x;
    if (b < 128) {
        int gid = b * 256 + threadIdx.x;        // 0..32767, 8 elems each
        int v = gid >> 6;
        int k = (gid & 63) * 8;
        f32x4 a = *(const f32x4*)(W + v * Cc + k);
        f32x4 c = *(const f32x4*)(W + v * Cc + k + 4);
        u16x8 o;
#pragma unroll
        for (int j = 0; j < 4; ++j) {
            o[j]     = f2bf(a[j]);
            o[4 + j] = f2bf(c[j]);
        }
        int frag = (v >> 4) * 16 + (k >> 5);
        int lane = (v & 15) + 16 * ((k >> 3) & 3);
        *(u16x8*)(&g_W2[frag * 512 + lane * 8]) = o;
    } else if (b < 528) {
        int gid = (b - 128) * 256 + threadIdx.x;   // 0..102399, 8 elems each
        f32x4 a = *(const f32x4*)(enc + gid * 8);
        f32x4 c = *(const f32x4*)(enc + gid * 8 + 4);
        f32x4 o0, o1;
#pragma unroll
        for (int j = 0; j < 4; ++j) { o0[j] = fast_tanh(a[j]); o1[j] = fast_tanh(c[j]); }
        *(f32x4*)(g_ta + gid * 8)     = o0;
        *(f32x4*)(g_ta + gid * 8 + 4) = o1;
    } else {
        int gid = (b - 528) * 256 + threadIdx.x;   // 0..25599, 8 elems each
        f32x4 a = *(const f32x4*)(pred + gid * 8);
        f32x4 c = *(const f32x4*)(pred + gid * 8 + 4);
        f32x4 o0, o1;
#pragma unroll
        for (int j = 0; j < 4; ++j) { o0[j] = fast_tanh(a[j]); o1[j] = fast_tanh(c[j]); }
        *(f32x4*)(g_tp + gid * 8)     = o0;
        *(f32x4*)(g_tp + gid * 8 + 4) = o1;
    }
}

__global__ __launch_bounds__(512, 4) void joiner_main(
    const float* __restrict__ bias,  // (512,)
    float* __restrict__ out)         // (160000, 512)
{
    __shared__ unsigned short As[BM * Cc];   // 64 KB, XOR-swizzled rows

    const int tid = threadIdx.x;
    const int bid = blockIdx.x;

    // ---- stage: A = tanh(enc+pred) via tanh-sum identity -> bf16 LDS ----
    {
        const int r = tid >> 3;          // 0..63 (tile row)
        const int q = tid & 7;           // k-interleave slot
        const int m  = bid * BM + r;
        const int et = m / 100;
        const int u  = m - et * 100;
        const int bb = m / 40000;
        const int pr = bb * 100 + u;
        const float* taP = g_ta + et * Cc;
        const float* tpP = g_tp + pr * Cc;
        char* asB = (char*)As;
        const int swz = (r & 7) << 4;
#pragma unroll
        for (int c = 0; c < 8; ++c) {
            const int k0 = q * 8 + c * 64;      // interleaved chunks: bank-spread
            f32x4 a0 = *(const f32x4*)(taP + k0);
            f32x4 a1 = *(const f32x4*)(taP + k0 + 4);
            f32x4 p0 = *(const f32x4*)(tpP + k0);
            f32x4 p1 = *(const f32x4*)(tpP + k0 + 4);
            u16x8 o;
#pragma unroll
            for (int j = 0; j < 4; ++j) {
                float n0 = a0[j] + p0[j];
                float d0 = __builtin_fmaf(a0[j], p0[j], 1.0f);
                o[j] = f2bf(n0 * __builtin_amdgcn_rcpf(d0));
                float n1 = a1[j] + p1[j];
                float d1 = __builtin_fmaf(a1[j], p1[j], 1.0f);
                o[4 + j] = f2bf(n1 * __builtin_amdgcn_rcpf(d1));
            }
            int byte = r * 1024 + k0 * 2;
            *(u16x8*)(asB + (byte ^ swz)) = o;
        }
    }
    __syncthreads();   // only barrier

    // ---- compute: 8 waves; wave w -> V slice [w*64, w*64+64) ----
    const int lane = tid & 63;
    const int w    = tid >> 6;
    const int lc   = lane & 15;
    const int lkB  = (lane >> 4) << 4;

    f32x4 acc[4][4];
#pragma unroll
    for (int i = 0; i < 4; ++i)
#pragma unroll
        for (int j = 0; j < 4; ++j)
            acc[i][j] = (f32x4){0.f, 0.f, 0.f, 0.f};

    const char* asB = (const char*)As;
    const unsigned short* wb = &g_W2[0];

    bf16x8 bcur[4], bnx[4];
#pragma unroll
    for (int j = 0; j < 4; ++j)
        bcur[j] = *(const bf16x8*)(wb + (((w * 4 + j) * 16 + 0) << 9) + lane * 8);

#pragma unroll 2
    for (int ks = 0; ks < 16; ++ks) {
        if (ks < 15) {
#pragma unroll
            for (int j = 0; j < 4; ++j)
                bnx[j] = *(const bf16x8*)(wb + (((w * 4 + j) * 16 + ks + 1) << 9) + lane * 8);
        }
        bf16x8 af[4];
#pragma unroll
        for (int i = 0; i < 4; ++i) {
            int row  = i * 16 + lc;
            int byte = row * 1024 + ks * 64 + lkB;
            byte ^= (row & 7) << 4;
            af[i] = *(const bf16x8*)(asB + byte);
        }
        __builtin_amdgcn_s_setprio(1);
#pragma unroll
        for (int i = 0; i < 4; ++i)
#pragma unroll
            for (int j = 0; j < 4; ++j)
                acc[i][j] = __builtin_amdgcn_mfma_f32_16x16x32_bf16(
                    af[i], bcur[j], acc[i][j], 0, 0, 0);
        __builtin_amdgcn_s_setprio(0);
#pragma unroll
        for (int j = 0; j < 4; ++j) bcur[j] = bnx[j];
    }

    // ---- epilogue: C/D layout col=lane&15, row=(lane>>4)*4+q ----
    const int lr = (lane >> 4) << 2;
    float bia[4];
#pragma unroll
    for (int j = 0; j < 4; ++j) bia[j] = bias[w * 64 + j * 16 + lc];
#pragma unroll
    for (int i = 0; i < 4; ++i) {
#pragma unroll
        for (int q = 0; q < 4; ++q) {
            int row = bid * BM + i * 16 + lr + q;
            float* op = out + row * Vv + w * 64;
#pragma unroll
            for (int j = 0; j < 4; ++j)
                op[j * 16 + lc] = acc[i][j][q] + bia[j];
        }
    }
}

extern "C" void kernel_launch(void* const* d_in, const int* in_sizes, int n_in,
                              void* d_out, int out_size, void* d_ws, size_t ws_size,
                              hipStream_t stream) {
    const float* enc  = (const float*)d_in[0];
    const float* pred = (const float*)d_in[1];
    const float* W    = (const float*)d_in[2];
    const float* bias = (const float*)d_in[3];
    float* out        = (float*)d_out;

    prep_kernel<<<628, 256, 0, stream>>>(W, enc, pred);
    // 160000 rows / BM=64 -> 2500 blocks, each does full V=512 with 8 waves
    joiner_main<<<2500, 512, 0, stream>>>(bias, out);
}